// Round 1
// baseline (566.006 us; speedup 1.0000x reference)
//
#include <hip/hip_runtime.h>
#include <cstdint>

#define M_DIM 8192   // B*S = 4*2048
#define N_DIM 4096   // D_OUT
#define K_DIM 4096   // D_IN

typedef __bf16 bf16x8 __attribute__((ext_vector_type(8)));
typedef float  f32x4  __attribute__((ext_vector_type(4)));

__device__ __forceinline__ unsigned short f32_to_bf16_rne(float f) {
  union { float f; uint32_t u; } v; v.f = f;
  uint32_t u = v.u + 0x7fffu + ((v.u >> 16) & 1u);
  return (unsigned short)(u >> 16);
}

// async global->LDS, 16B per lane. LDS dest must be wave-uniform base; HW
// scatters lane i to base + i*16.
__device__ __forceinline__ void gload_lds16(const unsigned short* g, unsigned short* l) {
  __builtin_amdgcn_global_load_lds(
      (const __attribute__((address_space(1))) unsigned int*)(uintptr_t)g,
      (__attribute__((address_space(3))) unsigned int*)(uintptr_t)l,
      16, 0, 0);
}

// --- x: fp32 -> bf16 + per-row sum.  one block (256 thr) per row of 4096 ---
__global__ __launch_bounds__(256) void convert_x_kernel(
    const float* __restrict__ x, unsigned short* __restrict__ xb,
    float* __restrict__ rowsum) {
  const int row = blockIdx.x;
  const float* xr = x + (size_t)row * K_DIM;
  unsigned short* xo = xb + (size_t)row * K_DIM;
  const int tid = threadIdx.x;
  float s = 0.f;
#pragma unroll
  for (int j = 0; j < K_DIM / 1024; ++j) {
    const int idx = j * 1024 + tid * 4;
    float4 v = *(const float4*)(xr + idx);
    s += v.x + v.y + v.z + v.w;
    ushort4 o;
    o.x = f32_to_bf16_rne(v.x);
    o.y = f32_to_bf16_rne(v.y);
    o.z = f32_to_bf16_rne(v.z);
    o.w = f32_to_bf16_rne(v.w);
    *(ushort4*)(xo + idx) = o;
  }
#pragma unroll
  for (int off = 32; off > 0; off >>= 1) s += __shfl_down(s, off, 64);
  __shared__ float wsum[4];
  if ((tid & 63) == 0) wsum[tid >> 6] = s;
  __syncthreads();
  if (tid == 0) rowsum[row] = wsum[0] + wsum[1] + wsum[2] + wsum[3];
}

// --- weight_q: int32 (0..15, exact in bf16) -> bf16 ---
__global__ __launch_bounds__(256) void convert_w_kernel(
    const int* __restrict__ q, unsigned short* __restrict__ wb) {
  const int idx = (blockIdx.x * 256 + threadIdx.x) * 4;
  int4 v = *(const int4*)(q + idx);
  ushort4 o;
  o.x = f32_to_bf16_rne((float)v.x);
  o.y = f32_to_bf16_rne((float)v.y);
  o.z = f32_to_bf16_rne((float)v.z);
  o.w = f32_to_bf16_rne((float)v.w);
  *(ushort4*)(wb + idx) = o;
}

// --- GEMM: C[m,n] = sum_k A[m,k]*W[n,k]; epilogue y = scale*C - scale*zp*rowsum[m] + bias[n]
// 128x128 tile, BK=32, 256 thr (4 waves, 2x2 of 64x64), 4x4 mfma_16x16x32_bf16 per wave.
__global__ __launch_bounds__(256) void qlinear_gemm_kernel(
    const unsigned short* __restrict__ A,    // [M][K] bf16
    const unsigned short* __restrict__ Bm,   // [N][K] bf16
    const float* __restrict__ rowsum,        // [M]
    const float* __restrict__ scale_p, const float* __restrict__ zp_p,
    const float* __restrict__ bias,          // [N]
    float* __restrict__ out) {               // [M][N]
  __shared__ unsigned short sA[128 * 32];    // unpadded: required by global_load_lds
  __shared__ unsigned short sB[128 * 32];
  const int tid  = threadIdx.x;
  const int lane = tid & 63;
  const int wave = tid >> 6;
  const int bm = blockIdx.y * 128;
  const int bn = blockIdx.x * 128;
  const int wm = (wave & 1) * 64;
  const int wn = (wave >> 1) * 64;
  const int lr   = lane & 15;   // A-row / B-col within 16-tile
  const int quad = lane >> 4;   // k-chunk (8 elems) / output row quad

  // staging: lane i of wave w loads 16B: row = q64 + w*16 + i/4, col = (i%4)*8
  // -> LDS offset (elems) = q*2048 + w*512 + i*8  (lane-contiguous, matches HW scatter)
  const int ld_row = lane >> 2;
  const int ld_col = (lane & 3) * 8;
  const unsigned short* ag = A  + (size_t)(bm + wave * 16 + ld_row) * K_DIM + ld_col;
  const unsigned short* bg = Bm + (size_t)(bn + wave * 16 + ld_row) * K_DIM + ld_col;
  unsigned short* sa_dst = sA + wave * 512;
  unsigned short* sb_dst = sB + wave * 512;

  f32x4 acc[4][4] = {};

  for (int k0 = 0; k0 < K_DIM; k0 += 32) {
    gload_lds16(ag + k0,                       sa_dst);
    gload_lds16(ag + (size_t)64 * K_DIM + k0,  sa_dst + 2048);
    gload_lds16(bg + k0,                       sb_dst);
    gload_lds16(bg + (size_t)64 * K_DIM + k0,  sb_dst + 2048);
    __syncthreads();   // drains vmcnt -> LDS tiles valid

    bf16x8 av[4], bv[4];
#pragma unroll
    for (int i = 0; i < 4; ++i)
      av[i] = *(const bf16x8*)(sA + (wm + i * 16 + lr) * 32 + quad * 8);
#pragma unroll
    for (int j = 0; j < 4; ++j)
      bv[j] = *(const bf16x8*)(sB + (wn + j * 16 + lr) * 32 + quad * 8);
#pragma unroll
    for (int i = 0; i < 4; ++i)
#pragma unroll
      for (int j = 0; j < 4; ++j)
        acc[i][j] = __builtin_amdgcn_mfma_f32_16x16x32_bf16(av[i], bv[j], acc[i][j], 0, 0, 0);
    __syncthreads();   // all reads done before next stage overwrites
  }

  const float scale = *scale_p;
  const float szp   = scale * (*zp_p);
  // C/D layout: col = lane&15, row = quad*4 + reg  [m89-verified]
#pragma unroll
  for (int i = 0; i < 4; ++i) {
    const int gm0 = bm + wm + i * 16 + quad * 4;
    float rs[4];
#pragma unroll
    for (int r = 0; r < 4; ++r) rs[r] = szp * rowsum[gm0 + r];
#pragma unroll
    for (int j = 0; j < 4; ++j) {
      const int gn = bn + wn + j * 16 + lr;
      const float bb = bias[gn];
#pragma unroll
      for (int r = 0; r < 4; ++r)
        out[(size_t)(gm0 + r) * N_DIM + gn] = scale * acc[i][j][r] - rs[r] + bb;
    }
  }
}

extern "C" void kernel_launch(void* const* d_in, const int* in_sizes, int n_in,
                              void* d_out, int out_size, void* d_ws, size_t ws_size,
                              hipStream_t stream) {
  const float* x     = (const float*)d_in[0];
  const int*   wq    = (const int*)d_in[1];
  const float* scale = (const float*)d_in[2];
  const float* zp    = (const float*)d_in[3];
  const float* bias  = (const float*)d_in[4];
  float* out = (float*)d_out;

  // ws layout: xb (8192*4096 bf16 = 64MB) | wb (4096*4096 bf16 = 32MB) | rowsum (8192 f32)
  unsigned short* xb = (unsigned short*)d_ws;
  unsigned short* wb = xb + (size_t)M_DIM * K_DIM;
  float* rowsum = (float*)(wb + (size_t)N_DIM * K_DIM);

  convert_x_kernel<<<M_DIM, 256, 0, stream>>>(x, xb, rowsum);
  convert_w_kernel<<<(N_DIM * (K_DIM / 4)) / 256, 256, 0, stream>>>(wq, wb);
  dim3 grid(N_DIM / 128, M_DIM / 128);
  qlinear_gemm_kernel<<<grid, 256, 0, stream>>>(xb, wb, rowsum, scale, zp, bias, out);
}

// Round 2
// 561.136 us; speedup vs baseline: 1.0087x; 1.0087x over previous
//
#include <hip/hip_runtime.h>
#include <cstdint>

#define M_DIM 8192   // B*S = 4*2048
#define N_DIM 4096   // D_OUT
#define K_DIM 4096   // D_IN

typedef __bf16 bf16x8 __attribute__((ext_vector_type(8)));
typedef float  f32x4  __attribute__((ext_vector_type(4)));

__device__ __forceinline__ unsigned short f32_to_bf16_rne(float f) {
  union { float f; uint32_t u; } v; v.f = f;
  uint32_t u = v.u + 0x7fffu + ((v.u >> 16) & 1u);
  return (unsigned short)(u >> 16);
}

// async global->LDS, 16B per lane. LDS dest is wave-uniform base; HW
// scatters lane i to base + i*16.
__device__ __forceinline__ void gload_lds16(const unsigned short* g, unsigned short* l) {
  __builtin_amdgcn_global_load_lds(
      (const __attribute__((address_space(1))) unsigned int*)(uintptr_t)g,
      (__attribute__((address_space(3))) unsigned int*)(uintptr_t)l,
      16, 0, 0);
}

// --- fused prep: blocks [0,8192): x fp32->bf16 + rowsum; [8192,12288): w int->bf16
__global__ __launch_bounds__(256) void prep_kernel(
    const float* __restrict__ x, const int* __restrict__ q,
    unsigned short* __restrict__ xb, unsigned short* __restrict__ wb,
    float* __restrict__ rowsum) {
  const int tid = threadIdx.x;
  if (blockIdx.x < M_DIM) {
    const int row = blockIdx.x;
    const float* xr = x + (size_t)row * K_DIM;
    unsigned short* xo = xb + (size_t)row * K_DIM;
    float s = 0.f;
#pragma unroll
    for (int j = 0; j < K_DIM / 1024; ++j) {
      const int idx = j * 1024 + tid * 4;
      float4 v = *(const float4*)(xr + idx);
      s += v.x + v.y + v.z + v.w;
      ushort4 o;
      o.x = f32_to_bf16_rne(v.x);
      o.y = f32_to_bf16_rne(v.y);
      o.z = f32_to_bf16_rne(v.z);
      o.w = f32_to_bf16_rne(v.w);
      *(ushort4*)(xo + idx) = o;
    }
#pragma unroll
    for (int off = 32; off > 0; off >>= 1) s += __shfl_down(s, off, 64);
    __shared__ float wsum[4];
    if ((tid & 63) == 0) wsum[tid >> 6] = s;
    __syncthreads();
    if (tid == 0) rowsum[row] = wsum[0] + wsum[1] + wsum[2] + wsum[3];
  } else {
    const int row = blockIdx.x - M_DIM;
    const int* qr = q + (size_t)row * K_DIM;
    unsigned short* wo = wb + (size_t)row * K_DIM;
#pragma unroll
    for (int j = 0; j < K_DIM / 1024; ++j) {
      const int idx = j * 1024 + tid * 4;
      int4 v = *(const int4*)(qr + idx);
      ushort4 o;
      o.x = f32_to_bf16_rne((float)v.x);
      o.y = f32_to_bf16_rne((float)v.y);
      o.z = f32_to_bf16_rne((float)v.z);
      o.w = f32_to_bf16_rne((float)v.w);
      *(ushort4*)(wo + idx) = o;
    }
  }
}

// --- GEMM: C[m,n] = sum_k A[m,k]*W[n,k]; epilogue y = scale*C - scale*zp*rowsum[m] + bias[n]
// 128x128 tile, BK=32, 256 thr (4 waves, 2x2 of 64x64), 4x4 mfma_16x16x32_bf16 per wave.
// LDS layout XOR-swizzled: chunk c (16B) of row R stored at slot c ^ ((R>>1)&3).
// Realized on the load side by permuting each lane's SOURCE column (HW scatters
// lane i to lds_base + i*16); ds_read side applies the inverse -> conflict-free b128.
__global__ __launch_bounds__(256) void qlinear_gemm_kernel(
    const unsigned short* __restrict__ A,    // [M][K] bf16
    const unsigned short* __restrict__ Bm,   // [N][K] bf16
    const float* __restrict__ rowsum,        // [M]
    const float* __restrict__ scale_p, const float* __restrict__ zp_p,
    const float* __restrict__ bias,          // [N]
    float* __restrict__ out) {               // [M][N]
  __shared__ unsigned short sA[128 * 32];    // unpadded: required by global_load_lds
  __shared__ unsigned short sB[128 * 32];
  const int tid  = threadIdx.x;
  const int lane = tid & 63;
  const int wave = tid >> 6;
  const int bm = blockIdx.y * 128;
  const int bn = blockIdx.x * 128;
  const int wm = (wave & 1) * 64;
  const int wn = (wave >> 1) * 64;
  const int lr   = lane & 15;   // A-row / B-col within 16-tile
  const int quad = lane >> 4;   // k-chunk (8 elems) / output row quad

  // staging: lane i -> LDS slab offset i*16B = (row i>>2, slot i&3).
  // slot holds global chunk c = (i&3) ^ ((i>>3)&3)  [inverse of the swizzle]
  const int ld_row = lane >> 2;
  const int ld_col = ((lane & 3) ^ ((lane >> 3) & 3)) * 8;
  const unsigned short* ag = A  + (size_t)(bm + wave * 16 + ld_row) * K_DIM + ld_col;
  const unsigned short* bg = Bm + (size_t)(bn + wave * 16 + ld_row) * K_DIM + ld_col;
  unsigned short* sa_dst = sA + wave * 512;
  unsigned short* sb_dst = sB + wave * 512;

  // read-side swizzle slot: quad ^ ((R>>1)&3), R = (mult of 16) + lr
  const int swz = (quad ^ ((lr >> 1) & 3)) * 8;

  f32x4 acc[4][4] = {};

  for (int k0 = 0; k0 < K_DIM; k0 += 32) {
    gload_lds16(ag + k0,                       sa_dst);
    gload_lds16(ag + (size_t)64 * K_DIM + k0,  sa_dst + 2048);
    gload_lds16(bg + k0,                       sb_dst);
    gload_lds16(bg + (size_t)64 * K_DIM + k0,  sb_dst + 2048);
    __syncthreads();   // drains vmcnt -> LDS tiles valid

    bf16x8 av[4], bv[4];
#pragma unroll
    for (int i = 0; i < 4; ++i)
      av[i] = *(const bf16x8*)(sA + (wm + i * 16 + lr) * 32 + swz);
#pragma unroll
    for (int j = 0; j < 4; ++j)
      bv[j] = *(const bf16x8*)(sB + (wn + j * 16 + lr) * 32 + swz);
#pragma unroll
    for (int i = 0; i < 4; ++i)
#pragma unroll
      for (int j = 0; j < 4; ++j)
        acc[i][j] = __builtin_amdgcn_mfma_f32_16x16x32_bf16(av[i], bv[j], acc[i][j], 0, 0, 0);
    __syncthreads();   // all reads done before next stage overwrites
  }

  const float scale = *scale_p;
  const float szp   = scale * (*zp_p);
  // C/D layout: col = lane&15, row = quad*4 + reg  [m89-verified]
#pragma unroll
  for (int i = 0; i < 4; ++i) {
    const int gm0 = bm + wm + i * 16 + quad * 4;
    float rs[4];
#pragma unroll
    for (int r = 0; r < 4; ++r) rs[r] = szp * rowsum[gm0 + r];
#pragma unroll
    for (int j = 0; j < 4; ++j) {
      const int gn = bn + wn + j * 16 + lr;
      const float bb = bias[gn];
#pragma unroll
      for (int r = 0; r < 4; ++r)
        out[(size_t)(gm0 + r) * N_DIM + gn] = scale * acc[i][j][r] - rs[r] + bb;
    }
  }
}

extern "C" void kernel_launch(void* const* d_in, const int* in_sizes, int n_in,
                              void* d_out, int out_size, void* d_ws, size_t ws_size,
                              hipStream_t stream) {
  const float* x     = (const float*)d_in[0];
  const int*   wq    = (const int*)d_in[1];
  const float* scale = (const float*)d_in[2];
  const float* zp    = (const float*)d_in[3];
  const float* bias  = (const float*)d_in[4];
  float* out = (float*)d_out;

  // ws layout: xb (8192*4096 bf16 = 64MB) | wb (4096*4096 bf16 = 32MB) | rowsum (8192 f32)
  unsigned short* xb = (unsigned short*)d_ws;
  unsigned short* wb = xb + (size_t)M_DIM * K_DIM;
  float* rowsum = (float*)(wb + (size_t)N_DIM * K_DIM);

  prep_kernel<<<M_DIM + N_DIM, 256, 0, stream>>>(x, wq, xb, wb, rowsum);
  dim3 grid(N_DIM / 128, M_DIM / 128);
  qlinear_gemm_kernel<<<grid, 256, 0, stream>>>(xb, wb, rowsum, scale, zp, bias, out);
}

// Round 3
// 428.419 us; speedup vs baseline: 1.3211x; 1.3098x over previous
//
#include <hip/hip_runtime.h>
#include <cstdint>

#define M_DIM 8192   // B*S = 4*2048
#define N_DIM 4096   // D_OUT
#define K_DIM 4096   // D_IN

typedef int   i32x4 __attribute__((ext_vector_type(4)));
typedef float f32x4 __attribute__((ext_vector_type(4)));

// async global->LDS, 16B per lane. LDS dest is wave-uniform base; HW
// scatters lane i to base + i*16.
__device__ __forceinline__ void gload_lds16(const void* g, void* l) {
  __builtin_amdgcn_global_load_lds(
      (const __attribute__((address_space(1))) unsigned int*)(uintptr_t)g,
      (__attribute__((address_space(3))) unsigned int*)(uintptr_t)l,
      16, 0, 0);
}

// --- prep: blocks [0,8192): x fp32 -> int8 per-row symmetric quant, emit
//     sx[row]=rowmax/127 and si[row]=sum of int8 values (exact int sum).
//     blocks [8192,12288): weight int32 (0..15) -> int8 (exact).
__global__ __launch_bounds__(256) void prep_kernel(
    const float* __restrict__ x, const int* __restrict__ q,
    signed char* __restrict__ xq, signed char* __restrict__ wq8,
    float* __restrict__ sx, float* __restrict__ si) {
  const int tid = threadIdx.x;
  if (blockIdx.x < M_DIM) {
    const int row = blockIdx.x;
    const float* xr = x + (size_t)row * K_DIM;
    signed char* xo = xq + (size_t)row * K_DIM;
    float4 v[4];
    float amax = 0.f;
#pragma unroll
    for (int j = 0; j < 4; ++j) {
      v[j] = *(const float4*)(xr + j * 1024 + tid * 4);
      amax = fmaxf(amax, fmaxf(fmaxf(fabsf(v[j].x), fabsf(v[j].y)),
                               fmaxf(fabsf(v[j].z), fabsf(v[j].w))));
    }
#pragma unroll
    for (int off = 32; off > 0; off >>= 1)
      amax = fmaxf(amax, __shfl_down(amax, off, 64));
    __shared__ float wred[4];
    __shared__ int   ired[4];
    if ((tid & 63) == 0) wred[tid >> 6] = amax;
    __syncthreads();
    amax = fmaxf(fmaxf(wred[0], wred[1]), fmaxf(wred[2], wred[3]));
    const float inv = amax > 0.f ? 127.f / amax : 0.f;
    int isum = 0;
#pragma unroll
    for (int j = 0; j < 4; ++j) {
      int ix = __float2int_rn(v[j].x * inv);
      int iy = __float2int_rn(v[j].y * inv);
      int iz = __float2int_rn(v[j].z * inv);
      int iw = __float2int_rn(v[j].w * inv);
      isum += ix + iy + iz + iw;
      char4 o; o.x = (char)ix; o.y = (char)iy; o.z = (char)iz; o.w = (char)iw;
      *(char4*)(xo + j * 1024 + tid * 4) = o;
    }
#pragma unroll
    for (int off = 32; off > 0; off >>= 1)
      isum += __shfl_down(isum, off, 64);
    if ((tid & 63) == 0) ired[tid >> 6] = isum;
    __syncthreads();
    if (tid == 0) {
      sx[row] = amax * (1.f / 127.f);
      si[row] = (float)(ired[0] + ired[1] + ired[2] + ired[3]);
    }
  } else {
    const int row = blockIdx.x - M_DIM;
    const int* qr = q + (size_t)row * K_DIM;
    signed char* wo = wq8 + (size_t)row * K_DIM;
#pragma unroll
    for (int j = 0; j < 4; ++j) {
      const int idx = j * 1024 + tid * 4;
      int4 v = *(const int4*)(qr + idx);
      char4 o; o.x = (char)v.x; o.y = (char)v.y; o.z = (char)v.z; o.w = (char)v.w;
      *(char4*)(wo + idx) = o;
    }
  }
}

// --- GEMM i8: C[m,n] = sum_k xi[m,k]*q8[n,k] (i32, exact)
// epilogue: y = scale*sx[m]*(C - zp*si[m]) + bias[n]
// 128x128 tile, BK=64 int8 (64B rows = 4x16B chunks -> same swizzle geometry
// as the bf16 version that measured 0 bank conflicts), 256 thr (4 waves),
// 4x4 mfma_i32_16x16x64_i8 per wave per K-iter, 64 iters.
__global__ __launch_bounds__(256) void qlinear_gemm_kernel(
    const signed char* __restrict__ A,     // [M][K] int8
    const signed char* __restrict__ Bm,    // [N][K] int8
    const float* __restrict__ sx,          // [M] per-row x scale
    const float* __restrict__ si,          // [M] per-row int sum
    const float* __restrict__ scale_p, const float* __restrict__ zp_p,
    const float* __restrict__ bias,        // [N]
    float* __restrict__ out) {             // [M][N] fp32
  __shared__ signed char sA[128 * 64];     // 8 KB, unpadded (global_load_lds)
  __shared__ signed char sB[128 * 64];
  const int tid  = threadIdx.x;
  const int lane = tid & 63;
  const int wave = tid >> 6;
  const int bm = blockIdx.y * 128;
  const int bn = blockIdx.x * 128;
  const int wm = (wave & 1) * 64;
  const int wn = (wave >> 1) * 64;
  const int lr   = lane & 15;   // A-row / B-col within 16-tile
  const int quad = lane >> 4;   // k-chunk (16 int8) / output row quad

  // staging: lane i -> LDS slab offset i*16B = (row i>>2, slot i&3);
  // slot holds global 16B chunk c = (i&3) ^ ((i>>3)&3)   [XOR swizzle]
  const int ld_row = lane >> 2;
  const int ld_col = ((lane & 3) ^ ((lane >> 3) & 3)) * 16;
  const signed char* ag = A  + (size_t)(bm + wave * 16 + ld_row) * K_DIM + ld_col;
  const signed char* bg = Bm + (size_t)(bn + wave * 16 + ld_row) * K_DIM + ld_col;
  signed char* sa_dst = sA + wave * 1024;
  signed char* sb_dst = sB + wave * 1024;

  // read-side swizzle: chunk quad of row R lives at slot quad ^ ((R>>1)&3)
  const int swz = (quad ^ ((lr >> 1) & 3)) * 16;

  i32x4 acc[4][4] = {};

  for (int k0 = 0; k0 < K_DIM; k0 += 64) {
    gload_lds16(ag + k0,                       sa_dst);
    gload_lds16(ag + (size_t)64 * K_DIM + k0,  sa_dst + 4096);
    gload_lds16(bg + k0,                       sb_dst);
    gload_lds16(bg + (size_t)64 * K_DIM + k0,  sb_dst + 4096);
    __syncthreads();   // drains vmcnt -> LDS tiles valid

    i32x4 av[4], bv[4];
#pragma unroll
    for (int i = 0; i < 4; ++i)
      av[i] = *(const i32x4*)(sA + (wm + i * 16 + lr) * 64 + swz);
#pragma unroll
    for (int j = 0; j < 4; ++j)
      bv[j] = *(const i32x4*)(sB + (wn + j * 16 + lr) * 64 + swz);
#pragma unroll
    for (int i = 0; i < 4; ++i)
#pragma unroll
      for (int j = 0; j < 4; ++j)
        acc[i][j] = __builtin_amdgcn_mfma_i32_16x16x64_i8(av[i], bv[j], acc[i][j], 0, 0, 0);
    __syncthreads();   // all reads done before next stage overwrites
  }

  const float scale = *scale_p;
  const float zp    = *zp_p;
  // C/D layout: col = lane&15, row = quad*4 + reg (dtype-independent, m121-128)
#pragma unroll
  for (int i = 0; i < 4; ++i) {
    const int gm0 = bm + wm + i * 16 + quad * 4;
    float am[4], cm[4];
#pragma unroll
    for (int r = 0; r < 4; ++r) {
      am[r] = scale * sx[gm0 + r];
      cm[r] = -am[r] * zp * si[gm0 + r];
    }
#pragma unroll
    for (int j = 0; j < 4; ++j) {
      const int gn = bn + wn + j * 16 + lr;
      const float bb = bias[gn];
#pragma unroll
      for (int r = 0; r < 4; ++r)
        out[(size_t)(gm0 + r) * N_DIM + gn] =
            am[r] * (float)acc[i][j][r] + cm[r] + bb;
    }
  }
}

extern "C" void kernel_launch(void* const* d_in, const int* in_sizes, int n_in,
                              void* d_out, int out_size, void* d_ws, size_t ws_size,
                              hipStream_t stream) {
  const float* x     = (const float*)d_in[0];
  const int*   wq    = (const int*)d_in[1];
  const float* scale = (const float*)d_in[2];
  const float* zp    = (const float*)d_in[3];
  const float* bias  = (const float*)d_in[4];
  float* out = (float*)d_out;

  // ws: xq (8192*4096 i8 = 33.5MB) | wq8 (4096*4096 i8 = 16.8MB) | sx | si
  signed char* xq  = (signed char*)d_ws;
  signed char* wq8 = xq + (size_t)M_DIM * K_DIM;
  float* sx = (float*)(wq8 + (size_t)N_DIM * K_DIM);
  float* si = sx + M_DIM;

  prep_kernel<<<M_DIM + N_DIM, 256, 0, stream>>>(x, wq, xq, wq8, sx, si);
  dim3 grid(N_DIM / 128, M_DIM / 128);
  qlinear_gemm_kernel<<<grid, 256, 0, stream>>>(xq, wq8, sx, si, scale, zp, bias, out);
}